// Round 9
// baseline (143.122 us; speedup 1.0000x reference)
//
#include <hip/hip_runtime.h>
#include <float.h>

// Batched 1D linear interpolation with clamped extrapolation.
// t: [B,N] sorted fp32, v: [B,N] fp32, r: [B,M] fp32 -> out: [B,M] fp32
constexpr int B = 2048;
constexpr int N = 4096;
constexpr int M = 4096;
constexpr int K = 12288;  // 0.33 pts/bucket: window-4 fallback ~0.4%/query
constexpr int T = 512;
// LDS: stv (N+8)*8 + lut K*2 = 32832 + 24576 = 57408 B <= 64 KiB/workgroup
// (R8's 65600 B exceeded the 65536 static limit -> launch failure).
// 2 blocks/CU (114816 <= 160 KiB pool); launch_bounds(512,4): VGPR cap 128,
// 16 waves/CU. Design: trade TLP (32->16 waves) for MLP (8 queries x
// depth-2 LDS chain, wide b128 window reads).

__global__ __launch_bounds__(T, 4) void interp_kernel(
    const float* __restrict__ t,
    const float* __restrict__ v,
    const float* __restrict__ r,
    float* __restrict__ out) {
    __shared__ __align__(16) float2 stv[N + 8];  // (t,v) interleaved; pad = (+inf, 0)
    __shared__ unsigned short lut[K];            // lut[k] = first j with (int)(t[j]*K) >= k (<= N-1)

    const int tid = threadIdx.x;
    const int b = blockIdx.x;
    const float* tb = t + (size_t)b * N;
    const float* vb = v + (size_t)b * N;
    const float4* r4 = (const float4*)(r + (size_t)b * M);
    float4* o4 = (float4*)(out + (size_t)b * M);

    // ALL global loads upfront: 6 float4s in one vmcnt group.
    const float4 t4a = ((const float4*)tb)[tid];
    const float4 t4b = ((const float4*)tb)[tid + T];
    const float4 v4a = ((const float4*)vb)[tid];
    const float4 v4b = ((const float4*)vb)[tid + T];
    const float4 qa = r4[tid];
    const float4 qb = r4[tid + T];

    if (tid < 8) stv[N + tid] = make_float2(FLT_MAX, 0.0f);

    // Commit interleaved (t,v): two float4 LDS writes per staged float4 pair.
    {
        float4* s4 = (float4*)stv;
        s4[2 * tid + 0]       = make_float4(t4a.x, v4a.x, t4a.y, v4a.y);
        s4[2 * tid + 1]       = make_float4(t4a.z, v4a.z, t4a.w, v4a.w);
        s4[2 * (tid + T) + 0] = make_float4(t4b.x, v4b.x, t4b.y, v4b.y);
        s4[2 * (tid + T) + 1] = make_float4(t4b.z, v4b.z, t4b.w, v4b.w);
    }

    // lut range-fill straight from staged registers (single barrier).
    // Element j claims buckets ((int)(t[j-1]*K), (int)(t[j]*K)]; ranges are
    // disjoint and tile [0,K-1] completely (j==0 takes [0,..], j==N-1 extends
    // to K-1), so no init pass, no races; u16 LDS writes are byte-enable safe.
    {
        float tpa = __shfl_up(t4a.w, 1);
        if ((tid & 63) == 0 && tid > 0) tpa = tb[4 * tid - 1];
        float tpb = __shfl_up(t4b.w, 1);
        if ((tid & 63) == 0) tpb = tb[4 * (tid + T) - 1];
        const float pe[8] = {tpa, t4a.x, t4a.y, t4a.z, tpb, t4b.x, t4b.y, t4b.z};
        const float ce[8] = {t4a.x, t4a.y, t4a.z, t4a.w, t4b.x, t4b.y, t4b.z, t4b.w};
        #pragma unroll
        for (int e = 0; e < 8; ++e) {
            const int j = (e < 4 ? 4 * tid : 4 * (tid + T)) + (e & 3);
            int khi = (int)(ce[e] * (float)K);
            khi = khi > K - 1 ? K - 1 : khi;
            if (j == N - 1) khi = K - 1;        // claim the tail buckets
            const int klo = (j == 0) ? 0 : (int)(pe[e] * (float)K) + 1;
            for (int k = klo; k <= khi; ++k) lut[k] = (unsigned short)j;
        }
    }
    __syncthreads();

    const float tfirst = stv[0].x;
    const float vfirst = stv[0].y;
    const float tlast = stv[N - 1].x;
    const float vlast = stv[N - 1].y;

    // Query phase: 8-wide, chain depth 2 (lut -> window). Window = 2x
    // ds_read_b128 at 16B-aligned anchor; t and v both come from it.
    const float q[8] = {qa.x, qa.y, qa.z, qa.w, qb.x, qb.y, qb.z, qb.w};
    int b2[8];
    float4 wA[8], wB[8];
    float o[8];

    // Level 1: lut reads. Invariant: all j < lut[k] have bucket(t[j]) < k =
    // bucket(q) -> t[j] < q; b2 <= lut[k]-1, so t[b2] < q (except q < t[0],
    // handled by the c-clamp + final clamp).
    #pragma unroll
    for (int j = 0; j < 8; ++j) {
        int k = (int)(q[j] * (float)K);
        k = k < 0 ? 0 : (k > K - 1 ? K - 1 : k);
        int lo = lut[k];
        lo = lo < 1 ? 1 : lo;
        b2[j] = (lo - 1) & ~1;   // even float2 index -> 16B-aligned
    }
    // Level 2: 16 independent ds_read_b128 (forced-wide dests keep MLP alive).
    #pragma unroll
    for (int j = 0; j < 8; ++j) {
        const float4* w4 = (const float4*)(stv + b2[j]);
        wA[j] = w4[0];   // (t,v) of window pos 0,1
        wB[j] = w4[1];   // pos 2,3
    }
    // Resolve in registers + interp. idx = b2 + c, c = #{window t <= q}
    // (sorted prefix count = searchsorted-right within the window).
    #pragma unroll
    for (int j = 0; j < 8; ++j) {
        const float ta0 = wA[j].x, ta1 = wA[j].z, ta2 = wB[j].x, ta3 = wB[j].z;
        int c = (ta0 <= q[j] ? 1 : 0) + (ta1 <= q[j] ? 1 : 0) +
                (ta2 <= q[j] ? 1 : 0) + (ta3 <= q[j] ? 1 : 0);
        c = c < 1 ? 1 : c;   // q < t[0] handled by final clamp
        float t0 = (c >= 2) ? ((c >= 3) ? ta2 : ta1) : ta0;
        float t1 = (c >= 2) ? ((c >= 3) ? ta3 : ta2) : ta1;
        float v0 = (c >= 2) ? ((c >= 3) ? wB[j].y : wA[j].w) : wA[j].y;
        float v1 = (c >= 2) ? ((c >= 3) ? wB[j].w : wB[j].y) : wA[j].w;
        if (c == 4) {        // rare (~0.4%/query): transition past window
            float tp = ta3, vp = wB[j].w;
            int l = b2[j] + 4;
            float2 cur = stv[l];
            while (cur.x <= q[j]) { tp = cur.x; vp = cur.y; ++l; cur = stv[l]; }
            t0 = tp; t1 = cur.x; v0 = vp; v1 = cur.y;   // inf sentinels bound
        }
        // idx==N corner: t1=inf -> d=inf -> rcp=0 -> oo=v[N-1]; q==t[N-1]
        // corner: oo = v[N-1] since q==t1 there. Both match reference.
        const float d = t1 - t0;
        const float rden = __builtin_amdgcn_rcpf(d == 0.0f ? 1.0f : d);
        float oo = v0 + (q[j] - t0) * rden * (v1 - v0);
        oo = (q[j] < tfirst) ? vfirst : oo;
        oo = (q[j] > tlast) ? vlast : oo;
        o[j] = oo;
    }
    o4[tid]     = make_float4(o[0], o[1], o[2], o[3]);
    o4[tid + T] = make_float4(o[4], o[5], o[6], o[7]);
}

extern "C" void kernel_launch(void* const* d_in, const int* in_sizes, int n_in,
                              void* d_out, int out_size, void* d_ws, size_t ws_size,
                              hipStream_t stream) {
    const float* t = (const float*)d_in[0];
    const float* v = (const float*)d_in[1];
    const float* r = (const float*)d_in[2];
    float* out = (float*)d_out;
    interp_kernel<<<B, T, 0, stream>>>(t, v, r, out);
}

// Round 10
// 142.924 us; speedup vs baseline: 1.0014x; 1.0014x over previous
//
#include <hip/hip_runtime.h>
#include <float.h>

// Batched 1D linear interpolation with clamped extrapolation.
// t: [B,N] sorted fp32, v: [B,N] fp32, r: [B,M] fp32 -> out: [B,M] fp32
constexpr int B = 2048;
constexpr int N = 4096;
constexpr int M = 4096;
constexpr int K = 12256;  // 0.33 pts/bucket -> window-4 fallback ~0.07%/query
constexpr int T = 512;
// LDS: st (N+8)*4 + lut K*2 = 16416 + 24512 = 40928 B -> 4 blocks/CU (32 waves,
// HW cap). v is NOT staged: leaf v0/v1 come from global (L2-resident 16KB/batch),
// freeing 16.4KB of LDS for 3x lut density. Random LDS bank-words/query:
// 1 (lut) + 4 (st window) = 5, vs ~8.5 in the scan design -> conflicts drop.

__global__ __launch_bounds__(T, 8) void interp_kernel(
    const float* __restrict__ t,
    const float* __restrict__ v,
    const float* __restrict__ r,
    float* __restrict__ out) {
    __shared__ __align__(16) float st[N + 8];   // st[N..N+7] = +inf sentinels
    __shared__ unsigned short lut[K];           // lut[k] = first j with bucket(t[j]) >= k (<= N-1)

    const int tid = threadIdx.x;
    const int b = blockIdx.x;
    const float* tb = t + (size_t)b * N;
    const float* vb = v + (size_t)b * N;
    const float4* r4 = (const float4*)(r + (size_t)b * M);
    float4* o4 = (float4*)(out + (size_t)b * M);

    // ALL global loads upfront: one vmcnt group (t x2, r x2, boundary v's).
    const float4 t4a = ((const float4*)tb)[tid];
    const float4 t4b = ((const float4*)tb)[tid + T];
    const float4 qa = r4[tid];
    const float4 qb = r4[tid + T];
    const float vfirst = vb[0];
    const float vlast = vb[N - 1];

    if (tid < 8) st[N + tid] = FLT_MAX;
    ((float4*)st)[tid]     = t4a;
    ((float4*)st)[tid + T] = t4b;

    // lut range-fill straight from staged registers (single barrier).
    // Element j claims buckets ((int)(t[j-1]*K), (int)(t[j]*K)]; ranges are
    // disjoint and tile [0,K-1] (j==0 starts at 0, j==N-1 extends to K-1):
    // no init pass, no races; u16 LDS writes are byte-enable safe.
    {
        float tpa = __shfl_up(t4a.w, 1);
        if ((tid & 63) == 0 && tid > 0) tpa = tb[4 * tid - 1];
        float tpb = __shfl_up(t4b.w, 1);
        if ((tid & 63) == 0) tpb = tb[4 * (tid + T) - 1];
        const float pe[8] = {tpa, t4a.x, t4a.y, t4a.z, tpb, t4b.x, t4b.y, t4b.z};
        const float ce[8] = {t4a.x, t4a.y, t4a.z, t4a.w, t4b.x, t4b.y, t4b.z, t4b.w};
        #pragma unroll
        for (int e = 0; e < 8; ++e) {
            const int j = (e < 4 ? 4 * tid : 4 * (tid + T)) + (e & 3);
            int khi = (int)(ce[e] * (float)K);
            khi = khi > K - 1 ? K - 1 : khi;
            if (j == N - 1) khi = K - 1;        // claim the tail buckets
            const int klo = (j == 0) ? 0 : (int)(pe[e] * (float)K) + 1;
            for (int k = klo; k <= khi; ++k) lut[k] = (unsigned short)j;
        }
    }
    __syncthreads();

    const float tfirst = st[0];
    const float tlast = st[N - 1];

    const float q[8] = {qa.x, qa.y, qa.z, qa.w, qb.x, qb.y, qb.z, qb.w};
    int lo[8];
    float w0[8], w1[8], w2[8], w3[8];
    float tt0[8], tt1[8];
    int idx[8];
    float o[8];

    // Level 1: lut reads (8 independent u16).
    // Invariant: t[lut[k]-1] <= q < ... within a 1-bucket slack of lut[k].
    #pragma unroll
    for (int j = 0; j < 8; ++j) {
        int k = (int)(q[j] * (float)K);
        k = k < 0 ? 0 : (k > K - 1 ? K - 1 : k);
        int l = lut[k];
        lo[j] = l < 1 ? 1 : l;
    }
    // Level 2: 4-float windows st[lo-1..lo+2] (2x ds_read2_b32 each, no
    // alignment rounding -> scan reach is a uniform 2 past lo).
    #pragma unroll
    for (int j = 0; j < 8; ++j) {
        w0[j] = st[lo[j] - 1];
        w1[j] = st[lo[j] + 0];
        w2[j] = st[lo[j] + 1];
        w3[j] = st[lo[j] + 2];
    }
    // Resolve: idx = (lo-1) + c, c = #{window <= q} (sorted prefix count).
    #pragma unroll
    for (int j = 0; j < 8; ++j) {
        int c = (w0[j] <= q[j] ? 1 : 0) + (w1[j] <= q[j] ? 1 : 0) +
                (w2[j] <= q[j] ? 1 : 0) + (w3[j] <= q[j] ? 1 : 0);
        c = c < 1 ? 1 : c;                  // q < t[0]: fixed by final clamp
        float t0 = (c == 1) ? w0[j] : ((c == 2) ? w1[j] : w2[j]);
        float t1 = (c == 1) ? w1[j] : ((c == 2) ? w2[j] : w3[j]);
        int ix = lo[j] - 1 + c;
        if (c == 4) {                       // ~0.07%/query: walk past window
            float tp = w3[j];
            int l = lo[j] + 3;
            float tc = st[l];
            while (tc <= q[j]) { tp = tc; ++l; tc = st[l]; }  // inf-bounded
            t0 = tp; t1 = tc; ix = l;
        }
        tt0[j] = t0; tt1[j] = t1; idx[j] = ix;
    }
    // Level 3 (leaf): v pairs from GLOBAL (L2-resident), 16 independent dwords.
    // idx in [1, N]; read addr for v1 clamped to N-1 -- when idx==N, t1=inf
    // makes the v1 coefficient exactly 0, so the clamped value is harmless.
    float v0[8], v1[8];
    #pragma unroll
    for (int j = 0; j < 8; ++j) {
        const int i1 = idx[j] > N - 1 ? N - 1 : idx[j];
        v0[j] = vb[idx[j] - 1];
        v1[j] = vb[i1];
    }
    // Interp math (fast rcp). idx==N: d=inf -> rcp=0 -> oo=v0=v[N-1]. Matches
    // reference clamp; q<t[0] / q>t[N-1] overridden below.
    #pragma unroll
    for (int j = 0; j < 8; ++j) {
        const float d = tt1[j] - tt0[j];
        const float rden = __builtin_amdgcn_rcpf(d == 0.0f ? 1.0f : d);
        float oo = v0[j] + (q[j] - tt0[j]) * rden * (v1[j] - v0[j]);
        oo = (q[j] < tfirst) ? vfirst : oo;
        oo = (q[j] > tlast) ? vlast : oo;
        o[j] = oo;
    }
    o4[tid]     = make_float4(o[0], o[1], o[2], o[3]);
    o4[tid + T] = make_float4(o[4], o[5], o[6], o[7]);
}

extern "C" void kernel_launch(void* const* d_in, const int* in_sizes, int n_in,
                              void* d_out, int out_size, void* d_ws, size_t ws_size,
                              hipStream_t stream) {
    const float* t = (const float*)d_in[0];
    const float* v = (const float*)d_in[1];
    const float* r = (const float*)d_in[2];
    float* out = (float*)d_out;
    interp_kernel<<<B, T, 0, stream>>>(t, v, r, out);
}